// Round 1
// baseline (412.579 us; speedup 1.0000x reference)
//
#include <hip/hip_runtime.h>
#include <hip/hip_bf16.h>

#define BB 16
#define SS 2048
#define DD 64
#define NT_TILES (SS / 128)     // 16 k-tiles per batch
#define TILE_BYTES 16384        // one staged tile image (K or V^T), bf16 swizzled

typedef __attribute__((ext_vector_type(8)))  unsigned short ushort8;
typedef __attribute__((ext_vector_type(8)))  __bf16 bf16x8;
typedef __attribute__((ext_vector_type(16))) float f32x16;
typedef __attribute__((ext_vector_type(4)))  unsigned int uint4v;

static __device__ __forceinline__ unsigned short f2bf(float x) {
    return __builtin_bit_cast(unsigned short, __float2bfloat16(x));
}
static __device__ __forceinline__ unsigned pk2(float a, float b) {
    return (unsigned)f2bf(a) | ((unsigned)f2bf(b) << 16);
}
union F4 { float4 v; float a[4]; };

// width-16 async global->LDS copy (m193: width 4->16 = +67% staging).
// LDS dest is wave-uniform base + lane*16; global src is per-lane.
#define GLDS16(src, dst) __builtin_amdgcn_global_load_lds(                 \
    (const __attribute__((address_space(1))) unsigned int*)(src),          \
    (__attribute__((address_space(3))) unsigned int*)(dst), 16, 0, 0)

// ---------------------------------------------------------------------------
// Pre-pack: fp32 K,V -> bf16 swizzled 16KB tile images in workspace.
// One block per (k-tile, batch). Each image is byte-identical to what the main
// kernel's LDS staging used to produce, so the main kernel can stage with
// LINEAR global_load_lds copies (rule #21: pre-swizzled source + linear dest
// + swizzled read). This runs ONCE per launch instead of 64x per batch.
// ---------------------------------------------------------------------------
__global__ __launch_bounds__(256)
void prepack_kernel(const float* __restrict__ K, const float* __restrict__ V,
                    char* __restrict__ wsK, char* __restrict__ wsV) {
    __shared__ __align__(16) char smem[32768];
    char* Ks = smem;
    char* Vs = smem + 16384;
    const int t  = threadIdx.x;
    const int kt = blockIdx.x;
    const int b  = blockIdx.y;
    const float* Kg = K + (size_t)b * SS * DD;
    const float* Vg = V + (size_t)b * SS * DD;

    // K tile 128x64: flat coalesced float4 pairs -> swizzled b128 granules
    #pragma unroll
    for (int j = 0; j < 4; j++) {
        const int idx = 2 * t + 512 * j;
        const int row = idx >> 4;
        const int g   = (idx & 15) >> 1;
        const float* src = Kg + (size_t)(kt * 128) * DD + (size_t)idx * 4;
        F4 fa, fb; fa.v = *(const float4*)src; fb.v = *(const float4*)(src + 4);
        ushort8 u;
        #pragma unroll
        for (int e = 0; e < 4; e++) { u[e] = f2bf(fa.a[e]); u[e + 4] = f2bf(fb.a[e]); }
        *(ushort8*)(Ks + row * 128 + ((g ^ (row & 7)) * 16)) = u;
    }
    // V tile transposed: Vs[d][k], pitch 256, 16-granule XOR swizzle
    {
        const int d0v = (t & 15) * 4;
        const int kkb = (t >> 4) * 4;
        #pragma unroll
        for (int it2 = 0; it2 < 2; it2++) {
            const int kk = kkb + 64 * it2;
            const float* src = Vg + (size_t)(kt * 128 + kk) * DD + d0v;
            F4 r0, r1, r2, r3;
            r0.v = *(const float4*)(src);
            r1.v = *(const float4*)(src + DD);
            r2.v = *(const float4*)(src + 2 * DD);
            r3.v = *(const float4*)(src + 3 * DD);
            #pragma unroll
            for (int e = 0; e < 4; e++) {
                const int d = d0v + e;
                const uint2 wv = make_uint2(pk2(r0.a[e], r1.a[e]), pk2(r2.a[e], r3.a[e]));
                *(uint2*)(Vs + d * 256 + (((kk >> 3) ^ (d & 15)) * 16) + (kk & 7) * 2) = wv;
            }
        }
    }
    __syncthreads();
    // linear dump of the finished images (fully coalesced both sides)
    char* dK = wsK + (size_t)(b * NT_TILES + kt) * TILE_BYTES;
    char* dV = wsV + (size_t)(b * NT_TILES + kt) * TILE_BYTES;
    #pragma unroll
    for (int j = 0; j < 4; j++) {
        *(float4*)(dK + t * 16 + j * 4096) = *(const float4*)(Ks + t * 16 + j * 4096);
        *(float4*)(dV + t * 16 + j * 4096) = *(const float4*)(Vs + t * 16 + j * 4096);
    }
}

// ---------------------------------------------------------------------------
// Main kernel: identical compute/layout/epilogue to the verified r5 kernel;
// K/V staging replaced by 8 linear global_load_lds copies from the prepacked
// images (zero convert VALU, half the staged bytes). Mask loads nontemporal
// (268 MB zero-reuse stream; keep it out of L2 so K/V images stay resident).
// ---------------------------------------------------------------------------
__global__ __launch_bounds__(256, 4)
void sdpa_mfma_kernel(const float* __restrict__ Q, const char* __restrict__ wsK,
                      const char* __restrict__ wsV, const unsigned int* __restrict__ M,
                      float* __restrict__ O) {
    // Ks 16K (128k x 64d bf16, pitch 128, 8-granule XOR swizzle)
    // Vs 16K (V^T: 64d x 128k bf16, pitch 256, 16-granule XOR swizzle)
    // Ms 4.25K (32q x 128k mask bytes, pitch 136); Qs overlaps Ms (pre-loop only)
    __shared__ __align__(16) char smem[37120];
    char* Ks = smem;
    char* Vs = smem + 16384;
    char* Ms = smem + 32768;
    char* Qs = smem + 32768;
    float* red  = (float*)smem;              // epilogue partials (24 KB < 32 KB)
    float* denx = (float*)(smem + 32768);    // epilogue den exchange

    const int t    = threadIdx.x;
    const int lane = t & 63;
    const int l31  = lane & 31;
    const int half = lane >> 5;
    const int kh   = t >> 6;          // wave = k-chunk 32*kh of the 128-tile
    const int b    = blockIdx.y;
    const int q0   = blockIdx.x * 32;

    const unsigned int* Mg = M + (size_t)b * SS * SS + (size_t)q0 * SS;

    // ---- stage Q (pre-scaled by 1/temperature), swizzled bf16 ----
    {
        const int sr = t >> 3, sc = t & 7;
        const float* src = Q + ((size_t)b * SS + q0 + sr) * DD + sc * 8;
        F4 f0, f1; f0.v = *(const float4*)src; f1.v = *(const float4*)(src + 4);
        ushort8 u;
        #pragma unroll
        for (int e = 0; e < 4; e++) {
            u[e]     = f2bf(f0.a[e] * 0.125f);
            u[e + 4] = f2bf(f1.a[e] * 0.125f);
        }
        *(ushort8*)(Qs + sr * 128 + ((sc ^ (sr & 7)) * 16)) = u;
    }
    __syncthreads();

    // ---- preload Q fragments (B operand); all 4 waves share the q-tile ----
    const int qrow = l31;
    bf16x8 bq[4];
    #pragma unroll
    for (int dc = 0; dc < 4; dc++)
        bq[dc] = __builtin_bit_cast(bf16x8, *(const ushort8*)(
            Qs + qrow * 128 + (((2 * dc + half) ^ (qrow & 7)) * 16)));
    __syncthreads();   // Qs region becomes Ms from here on

    f32x16 On0, On1;
    #pragma unroll
    for (int i = 0; i < 16; i++) { On0[i] = 0.f; On1[i] = 0.f; }
    float den_acc = 0.f;

    const int krow = 32 * kh + l31;

    for (int kt = 0; kt < NT_TILES; ++kt) {
        // ---- stage K,V: linear async copies of prepacked swizzled images ----
        const char* tK = wsK + (size_t)(b * NT_TILES + kt) * TILE_BYTES;
        const char* tV = wsV + (size_t)(b * NT_TILES + kt) * TILE_BYTES;
        #pragma unroll
        for (int j = 0; j < 4; j++) {
            GLDS16(tK + t * 16 + j * 4096, Ks + kh * 1024 + j * 4096);
            GLDS16(tV + t * 16 + j * 4096, Vs + kh * 1024 + j * 4096);
        }
        // ---- stage mask tile: nontemporal int32 words -> bytes, pitch 136 ----
        {
            const int sr = t >> 3, sc = t & 7;
            const unsigned int* Mw = Mg + (size_t)sr * SS + kt * 128 + sc * 16;
            unsigned wd[4];
            #pragma unroll
            for (int g = 0; g < 4; g++) {
                const uint4v u = __builtin_nontemporal_load((const uint4v*)(Mw + 4 * g));
                wd[g] = (u[0] ? 1u : 0u) | (u[1] ? 0x100u : 0u) |
                        (u[2] ? 0x10000u : 0u) | (u[3] ? 0x1000000u : 0u);
            }
            *(uint2*)(Ms + sr * 136 + sc * 16)     = make_uint2(wd[0], wd[1]);
            *(uint2*)(Ms + sr * 136 + sc * 16 + 8) = make_uint2(wd[2], wd[3]);
        }
        __syncthreads();   // compiler drains vmcnt (global_load_lds) here

        // ---- QK^T: S^T tile [32k x 32q] for this wave's k-chunk ----
        f32x16 S;
        #pragma unroll
        for (int i = 0; i < 16; i++) S[i] = 0.f;
        #pragma unroll
        for (int dc = 0; dc < 4; dc++) {
            bf16x8 ak = __builtin_bit_cast(bf16x8, *(const ushort8*)(
                Ks + krow * 128 + (((2 * dc + half) ^ (krow & 7)) * 16)));
            S = __builtin_amdgcn_mfma_f32_32x32x16_bf16(ak, bq[dc], S, 0, 0, 0);
        }

        // ---- mask + exp + denominator (C row = e + 8g + 4half) ----
        float p[16];
        #pragma unroll
        for (int g = 0; g < 4; g++) {
            const unsigned mw = *(const unsigned*)(Ms + qrow * 136 + 32 * kh + 8 * g + 4 * half);
            #pragma unroll
            for (int e = 0; e < 4; e++) {
                const float ev = __expf(S[4 * g + e]);
                const float pv = ((mw >> (8 * e)) & 0xffu) ? 1.0f : ev;
                p[4 * g + e] = pv;
                den_acc += pv;
            }
        }

        // ---- P·V: B-operand frags via shfl_xor(32) (proven r5), 2 ksubs ----
        #pragma unroll
        for (int s2 = 0; s2 < 2; s2++) {
            const unsigned o0 = pk2(p[8 * s2 + 0], p[8 * s2 + 1]);
            const unsigned o1 = pk2(p[8 * s2 + 2], p[8 * s2 + 3]);
            const unsigned o2 = pk2(p[8 * s2 + 4], p[8 * s2 + 5]);
            const unsigned o3 = pk2(p[8 * s2 + 6], p[8 * s2 + 7]);
            const unsigned s0 = half ? o0 : o2;
            const unsigned s1 = half ? o1 : o3;
            const unsigned r0 = (unsigned)__shfl_xor((int)s0, 32, 64);
            const unsigned r1 = (unsigned)__shfl_xor((int)s1, 32, 64);
            uint4 bu;
            bu.x = half ? r0 : o0;
            bu.y = half ? r1 : o1;
            bu.z = half ? o2 : r0;
            bu.w = half ? o3 : r1;
            const bf16x8 bp = __builtin_bit_cast(bf16x8, bu);
            #pragma unroll
            for (int dc = 0; dc < 2; dc++) {
                const int vrow = 32 * dc + l31;
                bf16x8 av = __builtin_bit_cast(bf16x8, *(const ushort8*)(
                    Vs + vrow * 256 + (((4 * kh + 2 * s2 + half) ^ (vrow & 15)) * 16)));
                if (dc == 0) On0 = __builtin_amdgcn_mfma_f32_32x32x16_bf16(av, bp, On0, 0, 0, 0);
                else         On1 = __builtin_amdgcn_mfma_f32_32x32x16_bf16(av, bp, On1, 0, 0, 0);
            }
        }
        __syncthreads();
    }

    // ---- epilogue: lane halves, then 4-way k-split reduction via LDS ----
    const float den_tot = den_acc + __shfl_xor(den_acc, 32, 64);

    __syncthreads();
    if (kh != 0) {
        #pragma unroll
        for (int dc = 0; dc < 2; dc++)
            #pragma unroll
            for (int g = 0; g < 4; g++) {
                const f32x16& Oc = dc ? On1 : On0;
                float4 st;
                st.x = Oc[4 * g + 0]; st.y = Oc[4 * g + 1];
                st.z = Oc[4 * g + 2]; st.w = Oc[4 * g + 3];
                *(float4*)((char*)red + (kh - 1) * 8192 + (dc * 4 + g) * 1024 + lane * 16) = st;
            }
        if (lane < 32) denx[kh * 32 + l31] = den_tot;
    }
    __syncthreads();
    if (kh == 0) {
        const float inv = 1.0f / (den_tot + denx[32 + l31] + denx[64 + l31] + denx[96 + l31]);
        float* Og = O + ((size_t)b * SS + q0 + qrow) * DD;
        #pragma unroll
        for (int dc = 0; dc < 2; dc++)
            #pragma unroll
            for (int g = 0; g < 4; g++) {
                const f32x16& Oc = dc ? On1 : On0;
                float4 st;
                st.x = Oc[4 * g + 0]; st.y = Oc[4 * g + 1];
                st.z = Oc[4 * g + 2]; st.w = Oc[4 * g + 3];
                #pragma unroll
                for (int w2 = 0; w2 < 3; w2++) {
                    const float4 pr = *(const float4*)((char*)red + w2 * 8192 +
                                                       (dc * 4 + g) * 1024 + lane * 16);
                    st.x += pr.x; st.y += pr.y; st.z += pr.z; st.w += pr.w;
                }
                st.x *= inv; st.y *= inv; st.z *= inv; st.w *= inv;
                // d = e + 8g + 4half + 32dc  (C-row formula)
                *(float4*)(Og + 32 * dc + 8 * g + 4 * half) = st;
            }
    }
}

extern "C" void kernel_launch(void* const* d_in, const int* in_sizes, int n_in,
                              void* d_out, int out_size, void* d_ws, size_t ws_size,
                              hipStream_t stream) {
    const float* q = (const float*)d_in[0];
    const float* k = (const float*)d_in[1];
    const float* v = (const float*)d_in[2];
    const unsigned int* m = (const unsigned int*)d_in[3];
    float* out = (float*)d_out;

    // workspace: 4 MB K images + 4 MB V images (bf16, swizzled tile layout)
    char* wsK = (char*)d_ws;
    char* wsV = (char*)d_ws + (size_t)BB * NT_TILES * TILE_BYTES;

    dim3 pgrid(NT_TILES, BB);           // 16 x 16 = 256 blocks, 1 per CU
    prepack_kernel<<<pgrid, 256, 0, stream>>>(k, v, wsK, wsV);

    dim3 grid(SS / 32, BB);             // 64 x 16 = 1024 blocks -> 4 per CU
    sdpa_mfma_kernel<<<grid, 256, 0, stream>>>(q, wsK, wsV, m, out);
}